// Round 13
// baseline (239.714 us; speedup 1.0000x reference)
//
#include <hip/hip_runtime.h>
#include <hip/hip_bf16.h>

#define DIN 512
#define HID 512

#define AS1 __attribute__((address_space(1)))
#define AS3 __attribute__((address_space(3)))

typedef __attribute__((ext_vector_type(8))) short bfrag;     // 8 bf16 (4 VGPRs)
typedef __attribute__((ext_vector_type(4))) float ffrag;     // 4 fp32 acc
typedef __attribute__((ext_vector_type(8))) unsigned short u16x8;
typedef __attribute__((ext_vector_type(4))) unsigned short u16x4;

// ---------------------------------------------------------------------------
// Prelude: convert x->bf16 (padded), transpose+cvt both weights, count edges.
// ---------------------------------------------------------------------------
__global__ __launch_bounds__(256) void prelude(const float* __restrict__ x,
                                               unsigned short* __restrict__ xb,
                                               const float* __restrict__ W1,
                                               const float* __restrict__ W2,
                                               unsigned short* __restrict__ Wt1,
                                               unsigned short* __restrict__ Wt2,
                                               const int* __restrict__ dst,
                                               int* __restrict__ cnt,
                                               int E, int Nvalid, int C1) {
    int b = blockIdx.x;
    if (b < C1) {
        int idx = b * 256 + threadIdx.x;
        int row = idx >> 6;
        int c = (idx & 63) * 8;
        unsigned short o[8];
        if (row < Nvalid) {
            float4 a = *(const float4*)&x[(size_t)row * 512 + c];
            float4 v = *(const float4*)&x[(size_t)row * 512 + c + 4];
            __hip_bfloat16 t;
            t = __float2bfloat16(a.x); o[0] = *(unsigned short*)&t;
            t = __float2bfloat16(a.y); o[1] = *(unsigned short*)&t;
            t = __float2bfloat16(a.z); o[2] = *(unsigned short*)&t;
            t = __float2bfloat16(a.w); o[3] = *(unsigned short*)&t;
            t = __float2bfloat16(v.x); o[4] = *(unsigned short*)&t;
            t = __float2bfloat16(v.y); o[5] = *(unsigned short*)&t;
            t = __float2bfloat16(v.z); o[6] = *(unsigned short*)&t;
            t = __float2bfloat16(v.w); o[7] = *(unsigned short*)&t;
        } else {
#pragma unroll
            for (int j = 0; j < 8; ++j) o[j] = 0;
        }
        *(u16x8*)&xb[(size_t)row * 512 + c] = *(u16x8*)o;
    } else if (b < C1 + 512) {
        int bb = b - C1;
        int which = bb >> 8;
        bb &= 255;
        const float* W = which ? W2 : W1;
        unsigned short* Wt = which ? Wt2 : Wt1;
        __shared__ float t[32][33];
        int tid = threadIdx.x;
        int tx = tid & 31, ty = tid >> 5;          // 32 x 8
        int n0 = (bb & 15) * 32, k0 = (bb >> 4) * 32;
#pragma unroll
        for (int s = 0; s < 4; ++s)
            t[ty + 8 * s][tx] = W[(size_t)(k0 + ty + 8 * s) * 512 + n0 + tx];
        __syncthreads();
#pragma unroll
        for (int s = 0; s < 4; ++s) {
            __hip_bfloat16 v = __float2bfloat16(t[tx][ty + 8 * s]);
            Wt[(size_t)(n0 + ty + 8 * s) * 512 + k0 + tx] = *(unsigned short*)&v;
        }
    } else {
        int e = (b - C1 - 512) * 256 + threadIdx.x;
        if (e < E) atomicAdd(&cnt[dst[e]], 1);
    }
}

// ---------------------------------------------------------------------------
// scanA: per-block exclusive scan of cnt -> tmp, block totals -> bsum.
// ---------------------------------------------------------------------------
__global__ __launch_bounds__(256) void scanA(const int* __restrict__ cnt, int* __restrict__ tmp,
                                             int* __restrict__ bsum, int N) {
    int tid = threadIdx.x, lane = tid & 63, wave = tid >> 6;
    int i = blockIdx.x * 256 + tid;
    int v = (i < N) ? cnt[i] : 0;
    int incl = v;
#pragma unroll
    for (int o = 1; o < 64; o <<= 1) {
        int t = __shfl_up(incl, o);
        if (lane >= o) incl += t;
    }
    __shared__ int wtot[4];
    if (lane == 63) wtot[wave] = incl;
    __syncthreads();
    int woff = 0;
#pragma unroll
    for (int w = 0; w < 4; ++w) woff += (w < wave) ? wtot[w] : 0;
    if (i < N) tmp[i] = woff + incl - v;
    if (tid == 255) bsum[blockIdx.x] = woff + incl;
}

// ---------------------------------------------------------------------------
// scanB: per-block redundant reduce of bsum -> offs, cursor, dis, bias init.
// ---------------------------------------------------------------------------
__global__ __launch_bounds__(256) void scanB(const int* __restrict__ cnt,
                                             const int* __restrict__ tmp,
                                             const int* __restrict__ bsum,
                                             int* __restrict__ offs,
                                             int* __restrict__ cursor,
                                             float* __restrict__ dis,
                                             float* __restrict__ out,
                                             const float* __restrict__ bo,
                                             const float* __restrict__ bw,
                                             int N, int nb) {
    int tid = threadIdx.x;
    int lane = tid & 63, wv = tid >> 6;
    int v  = (tid < nb) ? bsum[tid] : 0;
    int vb = (tid < (int)blockIdx.x) ? v : 0;
    int a = v, bfr = vb;
#pragma unroll
    for (int o = 32; o > 0; o >>= 1) {
        a   += __shfl_down(a, o);
        bfr += __shfl_down(bfr, o);
    }
    __shared__ int sa[4], sb[4];
    if (lane == 0) { sa[wv] = a; sb[wv] = bfr; }
    __syncthreads();
    int totalE = sa[0] + sa[1] + sa[2] + sa[3];
    int before = sb[0] + sb[1] + sb[2] + sb[3];

    int i = blockIdx.x * 256 + tid;
    if (i < N) {
        int o = tmp[i] + before;
        offs[i] = o;
        cursor[i] = o;
        int d = cnt[i];
        dis[i] = rsqrtf((float)d + 1.0f);
        out[i] = bo[0];
        out[N + i] = bw[0];
    }
    if (blockIdx.x == 0 && tid == 0) offs[N] = totalE;
}

// ---------------------------------------------------------------------------
// fill: scatter edge records {src_byte_offset, full_weight} into csr2.
// ---------------------------------------------------------------------------
__global__ void fill_kernel(const int* __restrict__ src, const int* __restrict__ dst,
                            int* __restrict__ cursor, const float* __restrict__ dis,
                            int2* __restrict__ csr2, int E) {
    int e = blockIdx.x * 256 + threadIdx.x;
    if (e >= E) return;
    int d = dst[e];
    int s = src[e];
    int pos = atomicAdd(&cursor[d], 1);
    int2 rec;
    rec.x = s << 10;                           // byte offset into hw (HID*2 = 1024)
    rec.y = __float_as_int(dis[s] * dis[d]);   // full symmetric norm
    csr2[pos] = rec;
}

// ---------------------------------------------------------------------------
// XCD-swizzled tile mapping for the 128x256 GEMM.
// ---------------------------------------------------------------------------
__device__ inline bool tile_map2(int b, int Mtiles, int& m0, int& n0) {
    int xcd = b & 7, i = b >> 3;
    int nt = i & 1, mg = i >> 1;
    int mt = mg * 8 + xcd;
    if (mt >= Mtiles) return false;
    m0 = mt * 128;
    n0 = nt * 256;
    return true;
}

// bf16 MFMA GEMM, 128x256 tile, BK=64, XOR-swizzled LDS, operand-swapped
// mfma -> packed 8-B epilogue stores.  64 MFMA per 12 staging loads/iter.
__global__ __launch_bounds__(256, 2) void gemm_bf16(const short* __restrict__ A,
                                                    const short* __restrict__ B,
                                                    unsigned short* __restrict__ C,
                                                    int Mtiles) {
    __shared__ __align__(16) short As[128 * 64];   // 16 KB
    __shared__ __align__(16) short Bs[256 * 64];   // 32 KB
    const int K = 512;
    int m0, n0;
    if (!tile_map2(blockIdx.x, Mtiles, m0, n0)) return;
    int tid = threadIdx.x;
    int lane = tid & 63, wave = tid >> 6;
    int wm = (wave & 1) * 64;         // 2x2 waves: 64 m x 128 n each
    int wn = (wave >> 1) * 128;
    int r = lane & 15, q = lane >> 4;

    unsigned aoff[4]; int aldso[4];
#pragma unroll
    for (int i = 0; i < 4; ++i) {
        int s = i * 256 + tid;
        int row = s >> 3;
        int c = (s & 7) ^ (row & 7);
        aoff[i] = (unsigned)(m0 + row) * K + c * 8;
        aldso[i] = (i * 256 + (tid & ~63)) * 8;
    }
    unsigned boff[8]; int bldso[8];
#pragma unroll
    for (int i = 0; i < 8; ++i) {
        int s = i * 256 + tid;
        int row = s >> 3;
        int c = (s & 7) ^ (row & 7);
        boff[i] = (unsigned)(n0 + row) * K + c * 8;
        bldso[i] = (i * 256 + (tid & ~63)) * 8;
    }

    ffrag acc[4][8];
#pragma unroll
    for (int i = 0; i < 4; ++i)
#pragma unroll
        for (int j = 0; j < 8; ++j) acc[i][j] = ffrag{0.f, 0.f, 0.f, 0.f};

    for (int k0 = 0; k0 < K; k0 += 64) {
#pragma unroll
        for (int i = 0; i < 4; ++i)
            __builtin_amdgcn_global_load_lds((const AS1 void*)(A + aoff[i] + k0),
                                             (AS3 void*)(As + aldso[i]), 16, 0, 0);
#pragma unroll
        for (int i = 0; i < 8; ++i)
            __builtin_amdgcn_global_load_lds((const AS1 void*)(B + boff[i] + k0),
                                             (AS3 void*)(Bs + bldso[i]), 16, 0, 0);
        __syncthreads();

#pragma unroll
        for (int s2 = 0; s2 < 2; ++s2) {
            bfrag af[4], bfr[8];
#pragma unroll
            for (int i = 0; i < 4; ++i) {
                int arow = wm + i * 16 + r;
                int ach = (s2 * 4 + q) ^ (arow & 7);
                af[i] = *(const bfrag*)&As[arow * 64 + ach * 8];
            }
#pragma unroll
            for (int j = 0; j < 8; ++j) {
                int brow = wn + j * 16 + r;
                int bch = (s2 * 4 + q) ^ (brow & 7);
                bfr[j] = *(const bfrag*)&Bs[brow * 64 + bch * 8];
            }
#pragma unroll
            for (int i = 0; i < 4; ++i)
#pragma unroll
                for (int j = 0; j < 8; ++j)
                    acc[i][j] = __builtin_amdgcn_mfma_f32_16x16x32_bf16(bfr[j], af[i], acc[i][j], 0, 0, 0);
        }
        __syncthreads();
    }

#pragma unroll
    for (int i = 0; i < 4; ++i) {
        int m = m0 + wm + i * 16 + r;
#pragma unroll
        for (int j = 0; j < 8; ++j) {
            int n = n0 + wn + j * 16 + q * 4;
            u16x4 o;
#pragma unroll
            for (int reg = 0; reg < 4; ++reg) {
                __hip_bfloat16 v = __float2bfloat16(acc[i][j][reg]);
                o[reg] = *(unsigned short*)&v;
            }
            *(u16x4*)&C[(size_t)m * 512 + n] = o;
        }
    }
}

// ---------------------------------------------------------------------------
// XCD-sharded aggregation with batch-8 gathers + csr2 prefetch: shard =
// blockIdx&7 covers 64 channels (per-XCD footprint 3.2 MB -> L2 resident).
// Wave = 8 nodes, 8-lane cluster per node, lane loads u16x8 (16 B).
// Edge records for iteration k+1 are loaded while iteration k's 8 gathers
// are in flight -> csr2 latency off the critical chain.
// ---------------------------------------------------------------------------
__device__ inline void cvt8(u16x8 v, float* f) {
#pragma unroll
    for (int j = 0; j < 8; ++j) f[j] = __uint_as_float((unsigned)v[j] << 16);
}

__global__ __launch_bounds__(256) void agg_relu_sh(const unsigned short* __restrict__ hw,
                                                   const int2* __restrict__ csr2,
                                                   const int* __restrict__ offs,
                                                   const float* __restrict__ dis,
                                                   const float* __restrict__ bias,
                                                   unsigned short* __restrict__ out,
                                                   int N, int Mpad) {
    int b = blockIdx.x;
    int shard = b & 7;
    int tid = threadIdx.x;
    int wave = tid >> 6, lane = tid & 63;
    int cluster = lane >> 3;
    int sub = lane & 7;
    int node = (b >> 3) * 32 + wave * 8 + cluster;
    int c0 = shard * 64 + sub * 8;
    if (node >= N) {
        if (node < Mpad) {
            u16x8 z = {0, 0, 0, 0, 0, 0, 0, 0};
            *(u16x8*)&out[(size_t)node * HID + c0] = z;
        }
        return;
    }

    const char* hwb = (const char*)hw + c0 * 2;
    float dn = dis[node];
    int e0 = offs[node], e1 = offs[node + 1];

    float acc[8];
    {
        u16x8 sv = *(const u16x8*)&hw[(size_t)node * HID + c0];
        float g[8];
        cvt8(sv, g);
        float4 bb0 = *(const float4*)&bias[c0];
        float4 bb1 = *(const float4*)&bias[c0 + 4];
        float dis2 = dn * dn;
        acc[0] = g[0] * dis2 + bb0.x; acc[1] = g[1] * dis2 + bb0.y;
        acc[2] = g[2] * dis2 + bb0.z; acc[3] = g[3] * dis2 + bb0.w;
        acc[4] = g[4] * dis2 + bb1.x; acc[5] = g[5] * dis2 + bb1.y;
        acc[6] = g[6] * dis2 + bb1.z; acc[7] = g[7] * dis2 + bb1.w;
    }

    // prefetched edge records for the current batch
    int2 rec[8];
#pragma unroll
    for (int t = 0; t < 8; ++t) {
        int ee = e0 + t;
        rec[t] = csr2[(ee < e1) ? ee : (e1 - 1)];
    }

    for (int e = e0; e < e1; e += 8) {
        int off[8]; float wgt[8];
#pragma unroll
        for (int t = 0; t < 8; ++t) {
            off[t] = rec[t].x;
            wgt[t] = (e + t < e1) ? __int_as_float(rec[t].y) : 0.f;
        }
        // issue 8 independent gathers
        u16x8 v[8];
#pragma unroll
        for (int t = 0; t < 8; ++t)
            v[t] = *(const u16x8*)(hwb + off[t]);
        // prefetch next batch's records while gathers are in flight
        int en = e + 8;
        if (en < e1) {
#pragma unroll
            for (int t = 0; t < 8; ++t) {
                int ee = en + t;
                rec[t] = csr2[(ee < e1) ? ee : (e1 - 1)];
            }
        }
#pragma unroll
        for (int t = 0; t < 8; ++t) {
            float g[8];
            cvt8(v[t], g);
#pragma unroll
            for (int u = 0; u < 8; ++u) acc[u] += g[u] * wgt[t];
        }
    }

    unsigned short o[8];
#pragma unroll
    for (int t = 0; t < 8; ++t) {
        __hip_bfloat16 v = __float2bfloat16(fmaxf(acc[t], 0.f));
        o[t] = *(unsigned short*)&v;
    }
    *(u16x8*)&out[(size_t)node * HID + c0] = *(u16x8*)o;
}

// Layer-2 sharded aggregation + fused heads (batch-8 + prefetch).
__global__ __launch_bounds__(256) void agg_heads_sh(const unsigned short* __restrict__ hw,
                                                    const int2* __restrict__ csr2,
                                                    const int* __restrict__ offs,
                                                    const float* __restrict__ dis,
                                                    const float* __restrict__ bias,
                                                    const float* __restrict__ Wo,
                                                    const float* __restrict__ Ww,
                                                    float* __restrict__ out, int N) {
    int b = blockIdx.x;
    int shard = b & 7;
    int tid = threadIdx.x;
    int wave = tid >> 6, lane = tid & 63;
    int cluster = lane >> 3;
    int sub = lane & 7;
    int node = (b >> 3) * 32 + wave * 8 + cluster;
    if (node >= N) return;
    int c0 = shard * 64 + sub * 8;

    const char* hwb = (const char*)hw + c0 * 2;
    float dn = dis[node];
    int e0 = offs[node], e1 = offs[node + 1];

    float acc[8];
    {
        u16x8 sv = *(const u16x8*)&hw[(size_t)node * HID + c0];
        float g[8];
        cvt8(sv, g);
        float4 bb0 = *(const float4*)&bias[c0];
        float4 bb1 = *(const float4*)&bias[c0 + 4];
        float dis2 = dn * dn;
        acc[0] = g[0] * dis2 + bb0.x; acc[1] = g[1] * dis2 + bb0.y;
        acc[2] = g[2] * dis2 + bb0.z; acc[3] = g[3] * dis2 + bb0.w;
        acc[4] = g[4] * dis2 + bb1.x; acc[5] = g[5] * dis2 + bb1.y;
        acc[6] = g[6] * dis2 + bb1.z; acc[7] = g[7] * dis2 + bb1.w;
    }

    int2 rec[8];
#pragma unroll
    for (int t = 0; t < 8; ++t) {
        int ee = e0 + t;
        rec[t] = csr2[(ee < e1) ? ee : (e1 - 1)];
    }

    for (int e = e0; e < e1; e += 8) {
        int off[8]; float wgt[8];
#pragma unroll
        for (int t = 0; t < 8; ++t) {
            off[t] = rec[t].x;
            wgt[t] = (e + t < e1) ? __int_as_float(rec[t].y) : 0.f;
        }
        u16x8 v[8];
#pragma unroll
        for (int t = 0; t < 8; ++t)
            v[t] = *(const u16x8*)(hwb + off[t]);
        int en = e + 8;
        if (en < e1) {
#pragma unroll
            for (int t = 0; t < 8; ++t) {
                int ee = en + t;
                rec[t] = csr2[(ee < e1) ? ee : (e1 - 1)];
            }
        }
#pragma unroll
        for (int t = 0; t < 8; ++t) {
            float g[8];
            cvt8(v[t], g);
#pragma unroll
            for (int u = 0; u < 8; ++u) acc[u] += g[u] * wgt[t];
        }
    }

    float4 wo0 = *(const float4*)&Wo[c0];
    float4 wo1 = *(const float4*)&Wo[c0 + 4];
    float4 ww0 = *(const float4*)&Ww[c0];
    float4 ww1 = *(const float4*)&Ww[c0 + 4];
    float po = 0.f, pw = 0.f, h;
    h = fmaxf(acc[0], 0.f); po += h * wo0.x; pw += h * ww0.x;
    h = fmaxf(acc[1], 0.f); po += h * wo0.y; pw += h * ww0.y;
    h = fmaxf(acc[2], 0.f); po += h * wo0.z; pw += h * ww0.z;
    h = fmaxf(acc[3], 0.f); po += h * wo0.w; pw += h * ww0.w;
    h = fmaxf(acc[4], 0.f); po += h * wo1.x; pw += h * ww1.x;
    h = fmaxf(acc[5], 0.f); po += h * wo1.y; pw += h * ww1.y;
    h = fmaxf(acc[6], 0.f); po += h * wo1.z; pw += h * ww1.z;
    h = fmaxf(acc[7], 0.f); po += h * wo1.w; pw += h * ww1.w;

#pragma unroll
    for (int off2 = 4; off2 > 0; off2 >>= 1) {
        po += __shfl_down(po, off2);
        pw += __shfl_down(pw, off2);
    }
    if (sub == 0) {
        atomicAdd(&out[node], po);
        atomicAdd(&out[N + node], pw);
    }
}

// ---------------------------------------------------------------------------
extern "C" void kernel_launch(void* const* d_in, const int* in_sizes, int n_in,
                              void* d_out, int out_size, void* d_ws, size_t ws_size,
                              hipStream_t stream) {
    const float* x  = (const float*)d_in[0];
    const int*   ei = (const int*)d_in[1];
    const float* W1 = (const float*)d_in[2];
    const float* b1 = (const float*)d_in[3];
    const float* W2 = (const float*)d_in[4];
    const float* b2 = (const float*)d_in[5];
    const float* Wo = (const float*)d_in[6];
    const float* bo = (const float*)d_in[7];
    const float* Ww = (const float*)d_in[8];
    const float* bw = (const float*)d_in[9];

    const int N = in_sizes[0] / DIN;           // 25000
    const int E = in_sizes[1] / 2;             // 200000
    const int Mpad = (N + 127) & ~127;         // 25088
    const int Mtiles = Mpad / 128;             // 196
    const int nb = (N + 255) / 256;            // 98
    const int C1 = Mpad / 4;                   // convert blocks
    const int EJ = (E + 255) / 256;            // edge blocks

    char* ws = (char*)d_ws;
    size_t p = 0;
    auto alloc = [&](size_t bytes) -> char* {
        char* r = ws + p;
        p += (bytes + 255) & ~(size_t)255;
        return r;
    };
    int*   cnt    = (int*)alloc((size_t)N * 4);
    int*   offs   = (int*)alloc((size_t)(N + 1) * 4);
    int*   cursor = (int*)alloc((size_t)N * 4);
    int*   tmp    = (int*)alloc((size_t)N * 4);
    int*   bsum   = (int*)alloc(132 * 4);
    float* dis    = (float*)alloc((size_t)N * 4);
    int2*  csr2   = (int2*)alloc((size_t)E * 8 + 64);
    unsigned short* xb  = (unsigned short*)alloc((size_t)Mpad * 512 * 2);
    unsigned short* Wt1 = (unsigned short*)alloc((size_t)512 * 512 * 2);
    unsigned short* Wt2 = (unsigned short*)alloc((size_t)512 * 512 * 2);
    unsigned short* hw  = (unsigned short*)alloc((size_t)Mpad * 512 * 2);
    unsigned short* h1  = (unsigned short*)alloc((size_t)Mpad * 512 * 2);

    const int* src = ei;
    const int* dst = ei + E;

    hipMemsetAsync(cnt, 0, (size_t)N * 4, stream);

    prelude<<<C1 + 512 + EJ, 256, 0, stream>>>(x, xb, W1, W2, Wt1, Wt2,
                                               dst, cnt, E, N, C1);
    scanA<<<nb, 256, 0, stream>>>(cnt, tmp, bsum, N);
    scanB<<<nb, 256, 0, stream>>>(cnt, tmp, bsum, offs, cursor, dis,
                                  (float*)d_out, bo, bw, N, nb);
    fill_kernel<<<EJ, 256, 0, stream>>>(src, dst, cursor, dis, csr2, E);

    const int ggrid = 8 * ((Mtiles + 7) / 8) * 2;   // 400 blocks, XCD-swizzled
    gemm_bf16<<<ggrid, 256, 0, stream>>>((const short*)xb, (const short*)Wt1, hw, Mtiles);
    agg_relu_sh<<<8 * (Mpad / 32), 256, 0, stream>>>(hw, csr2, offs, dis, b1, h1, N, Mpad);
    gemm_bf16<<<ggrid, 256, 0, stream>>>((const short*)h1, (const short*)Wt2, hw, Mtiles);
    agg_heads_sh<<<8 * ((N + 31) / 32), 256, 0, stream>>>(hw, csr2, offs, dis, b2,
                                                          Wo, Ww, (float*)d_out, N);
}

// Round 14
// 224.746 us; speedup vs baseline: 1.0666x; 1.0666x over previous
//
#include <hip/hip_runtime.h>
#include <hip/hip_bf16.h>

#define DIN 512
#define HID 512

#define AS1 __attribute__((address_space(1)))
#define AS3 __attribute__((address_space(3)))

typedef __attribute__((ext_vector_type(8))) short bfrag;     // 8 bf16 (4 VGPRs)
typedef __attribute__((ext_vector_type(4))) float ffrag;     // 4 fp32 acc
typedef __attribute__((ext_vector_type(8))) unsigned short u16x8;
typedef __attribute__((ext_vector_type(4))) unsigned short u16x4;

// ---------------------------------------------------------------------------
// Prelude: convert x->bf16 (padded), transpose+cvt both weights, count edges.
// ---------------------------------------------------------------------------
__global__ __launch_bounds__(256) void prelude(const float* __restrict__ x,
                                               unsigned short* __restrict__ xb,
                                               const float* __restrict__ W1,
                                               const float* __restrict__ W2,
                                               unsigned short* __restrict__ Wt1,
                                               unsigned short* __restrict__ Wt2,
                                               const int* __restrict__ dst,
                                               int* __restrict__ cnt,
                                               int E, int Nvalid, int C1) {
    int b = blockIdx.x;
    if (b < C1) {
        int idx = b * 256 + threadIdx.x;
        int row = idx >> 6;
        int c = (idx & 63) * 8;
        unsigned short o[8];
        if (row < Nvalid) {
            float4 a = *(const float4*)&x[(size_t)row * 512 + c];
            float4 v = *(const float4*)&x[(size_t)row * 512 + c + 4];
            __hip_bfloat16 t;
            t = __float2bfloat16(a.x); o[0] = *(unsigned short*)&t;
            t = __float2bfloat16(a.y); o[1] = *(unsigned short*)&t;
            t = __float2bfloat16(a.z); o[2] = *(unsigned short*)&t;
            t = __float2bfloat16(a.w); o[3] = *(unsigned short*)&t;
            t = __float2bfloat16(v.x); o[4] = *(unsigned short*)&t;
            t = __float2bfloat16(v.y); o[5] = *(unsigned short*)&t;
            t = __float2bfloat16(v.z); o[6] = *(unsigned short*)&t;
            t = __float2bfloat16(v.w); o[7] = *(unsigned short*)&t;
        } else {
#pragma unroll
            for (int j = 0; j < 8; ++j) o[j] = 0;
        }
        *(u16x8*)&xb[(size_t)row * 512 + c] = *(u16x8*)o;
    } else if (b < C1 + 512) {
        int bb = b - C1;
        int which = bb >> 8;
        bb &= 255;
        const float* W = which ? W2 : W1;
        unsigned short* Wt = which ? Wt2 : Wt1;
        __shared__ float t[32][33];
        int tid = threadIdx.x;
        int tx = tid & 31, ty = tid >> 5;          // 32 x 8
        int n0 = (bb & 15) * 32, k0 = (bb >> 4) * 32;
#pragma unroll
        for (int s = 0; s < 4; ++s)
            t[ty + 8 * s][tx] = W[(size_t)(k0 + ty + 8 * s) * 512 + n0 + tx];
        __syncthreads();
#pragma unroll
        for (int s = 0; s < 4; ++s) {
            __hip_bfloat16 v = __float2bfloat16(t[tx][ty + 8 * s]);
            Wt[(size_t)(n0 + ty + 8 * s) * 512 + k0 + tx] = *(unsigned short*)&v;
        }
    } else {
        int e = (b - C1 - 512) * 256 + threadIdx.x;
        if (e < E) atomicAdd(&cnt[dst[e]], 1);
    }
}

// ---------------------------------------------------------------------------
// scanA: per-block exclusive scan of cnt -> tmp, block totals -> bsum.
// ---------------------------------------------------------------------------
__global__ __launch_bounds__(256) void scanA(const int* __restrict__ cnt, int* __restrict__ tmp,
                                             int* __restrict__ bsum, int N) {
    int tid = threadIdx.x, lane = tid & 63, wave = tid >> 6;
    int i = blockIdx.x * 256 + tid;
    int v = (i < N) ? cnt[i] : 0;
    int incl = v;
#pragma unroll
    for (int o = 1; o < 64; o <<= 1) {
        int t = __shfl_up(incl, o);
        if (lane >= o) incl += t;
    }
    __shared__ int wtot[4];
    if (lane == 63) wtot[wave] = incl;
    __syncthreads();
    int woff = 0;
#pragma unroll
    for (int w = 0; w < 4; ++w) woff += (w < wave) ? wtot[w] : 0;
    if (i < N) tmp[i] = woff + incl - v;
    if (tid == 255) bsum[blockIdx.x] = woff + incl;
}

// ---------------------------------------------------------------------------
// scanB: per-block redundant reduce of bsum -> offs, cursor, dis, bias init.
// ---------------------------------------------------------------------------
__global__ __launch_bounds__(256) void scanB(const int* __restrict__ cnt,
                                             const int* __restrict__ tmp,
                                             const int* __restrict__ bsum,
                                             int* __restrict__ offs,
                                             int* __restrict__ cursor,
                                             float* __restrict__ dis,
                                             float* __restrict__ out,
                                             const float* __restrict__ bo,
                                             const float* __restrict__ bw,
                                             int N, int nb) {
    int tid = threadIdx.x;
    int lane = tid & 63, wv = tid >> 6;
    int v  = (tid < nb) ? bsum[tid] : 0;
    int vb = (tid < (int)blockIdx.x) ? v : 0;
    int a = v, bfr = vb;
#pragma unroll
    for (int o = 32; o > 0; o >>= 1) {
        a   += __shfl_down(a, o);
        bfr += __shfl_down(bfr, o);
    }
    __shared__ int sa[4], sb[4];
    if (lane == 0) { sa[wv] = a; sb[wv] = bfr; }
    __syncthreads();
    int totalE = sa[0] + sa[1] + sa[2] + sa[3];
    int before = sb[0] + sb[1] + sb[2] + sb[3];

    int i = blockIdx.x * 256 + tid;
    if (i < N) {
        int o = tmp[i] + before;
        offs[i] = o;
        cursor[i] = o;
        int d = cnt[i];
        dis[i] = rsqrtf((float)d + 1.0f);
        out[i] = bo[0];
        out[N + i] = bw[0];
    }
    if (blockIdx.x == 0 && tid == 0) offs[N] = totalE;
}

// ---------------------------------------------------------------------------
// XCD-swizzled tile mapping for the 128x256 GEMM.
// ---------------------------------------------------------------------------
__device__ inline bool tile_map2(int b, int Mtiles, int& m0, int& n0) {
    int xcd = b & 7, i = b >> 3;
    int nt = i & 1, mg = i >> 1;
    int mt = mg * 8 + xcd;
    if (mt >= Mtiles) return false;
    m0 = mt * 128;
    n0 = nt * 256;
    return true;
}

// Shared GEMM body: 128x256 tile, BK=64, XOR-swizzled LDS, operand-swapped
// mfma -> packed 8-B epilogue stores.  64 MFMA per 12 staging loads/iter.
__device__ __forceinline__ void gemm_body(const short* __restrict__ A,
                                          const short* __restrict__ B,
                                          unsigned short* __restrict__ C,
                                          int Mtiles, int bidx,
                                          short* As, short* Bs) {
    const int K = 512;
    int m0, n0;
    if (!tile_map2(bidx, Mtiles, m0, n0)) return;
    int tid = threadIdx.x;
    int lane = tid & 63, wave = tid >> 6;
    int wm = (wave & 1) * 64;         // 2x2 waves: 64 m x 128 n each
    int wn = (wave >> 1) * 128;
    int r = lane & 15, q = lane >> 4;

    unsigned aoff[4]; int aldso[4];
#pragma unroll
    for (int i = 0; i < 4; ++i) {
        int s = i * 256 + tid;
        int row = s >> 3;
        int c = (s & 7) ^ (row & 7);
        aoff[i] = (unsigned)(m0 + row) * K + c * 8;
        aldso[i] = (i * 256 + (tid & ~63)) * 8;
    }
    unsigned boff[8]; int bldso[8];
#pragma unroll
    for (int i = 0; i < 8; ++i) {
        int s = i * 256 + tid;
        int row = s >> 3;
        int c = (s & 7) ^ (row & 7);
        boff[i] = (unsigned)(n0 + row) * K + c * 8;
        bldso[i] = (i * 256 + (tid & ~63)) * 8;
    }

    ffrag acc[4][8];
#pragma unroll
    for (int i = 0; i < 4; ++i)
#pragma unroll
        for (int j = 0; j < 8; ++j) acc[i][j] = ffrag{0.f, 0.f, 0.f, 0.f};

    for (int k0 = 0; k0 < K; k0 += 64) {
#pragma unroll
        for (int i = 0; i < 4; ++i)
            __builtin_amdgcn_global_load_lds((const AS1 void*)(A + aoff[i] + k0),
                                             (AS3 void*)(As + aldso[i]), 16, 0, 0);
#pragma unroll
        for (int i = 0; i < 8; ++i)
            __builtin_amdgcn_global_load_lds((const AS1 void*)(B + boff[i] + k0),
                                             (AS3 void*)(Bs + bldso[i]), 16, 0, 0);
        __syncthreads();

#pragma unroll
        for (int s2 = 0; s2 < 2; ++s2) {
            bfrag af[4], bfr[8];
#pragma unroll
            for (int i = 0; i < 4; ++i) {
                int arow = wm + i * 16 + r;
                int ach = (s2 * 4 + q) ^ (arow & 7);
                af[i] = *(const bfrag*)&As[arow * 64 + ach * 8];
            }
#pragma unroll
            for (int j = 0; j < 8; ++j) {
                int brow = wn + j * 16 + r;
                int bch = (s2 * 4 + q) ^ (brow & 7);
                bfr[j] = *(const bfrag*)&Bs[brow * 64 + bch * 8];
            }
#pragma unroll
            for (int i = 0; i < 4; ++i)
#pragma unroll
                for (int j = 0; j < 8; ++j)
                    acc[i][j] = __builtin_amdgcn_mfma_f32_16x16x32_bf16(bfr[j], af[i], acc[i][j], 0, 0, 0);
        }
        __syncthreads();
    }

#pragma unroll
    for (int i = 0; i < 4; ++i) {
        int m = m0 + wm + i * 16 + r;
#pragma unroll
        for (int j = 0; j < 8; ++j) {
            int n = n0 + wn + j * 16 + q * 4;
            u16x4 o;
#pragma unroll
            for (int reg = 0; reg < 4; ++reg) {
                __hip_bfloat16 v = __float2bfloat16(acc[i][j][reg]);
                o[reg] = *(unsigned short*)&v;
            }
            *(u16x4*)&C[(size_t)m * 512 + n] = o;
        }
    }
}

// Layer-1 fused launch: blocks [0,G) run the GEMM; blocks [G,G+EJ) scatter
// edge records {src_byte_offset, full_weight} into csr2 (independent work,
// hidden under the GEMM's occupancy instead of a serial ~10 us launch).
__global__ __launch_bounds__(256, 2) void gemm_fill(const short* __restrict__ A,
                                                    const short* __restrict__ B,
                                                    unsigned short* __restrict__ C,
                                                    int Mtiles, int G,
                                                    const int* __restrict__ src,
                                                    const int* __restrict__ dst,
                                                    int* __restrict__ cursor,
                                                    const float* __restrict__ dis,
                                                    int2* __restrict__ csr2, int E) {
    __shared__ __align__(16) short As[128 * 64];   // 16 KB
    __shared__ __align__(16) short Bs[256 * 64];   // 32 KB
    int b = blockIdx.x;
    if (b < G) {
        gemm_body(A, B, C, Mtiles, b, As, Bs);
    } else {
        int e = (b - G) * 256 + threadIdx.x;
        if (e >= E) return;
        int d = dst[e];
        int s = src[e];
        int pos = atomicAdd(&cursor[d], 1);
        int2 rec;
        rec.x = s << 10;                           // byte offset into hw (HID*2 = 1024)
        rec.y = __float_as_int(dis[s] * dis[d]);   // full symmetric norm
        csr2[pos] = rec;
    }
}

// Layer-2 plain GEMM.
__global__ __launch_bounds__(256, 2) void gemm_bf16(const short* __restrict__ A,
                                                    const short* __restrict__ B,
                                                    unsigned short* __restrict__ C,
                                                    int Mtiles) {
    __shared__ __align__(16) short As[128 * 64];
    __shared__ __align__(16) short Bs[256 * 64];
    gemm_body(A, B, C, Mtiles, blockIdx.x, As, Bs);
}

// ---------------------------------------------------------------------------
// XCD-sharded aggregation (R12-proven): shard = blockIdx&7 covers 64 channels
// (per-XCD gather footprint 3.2 MB -> L2 resident).  Wave = 8 nodes, 8-lane
// cluster per node, lane loads u16x8 (16 B).  Batch-4 edge gathers.  Edge
// records carry byte offsets + precomputed weights.
// ---------------------------------------------------------------------------
__device__ inline void cvt8(u16x8 v, float* f) {
#pragma unroll
    for (int j = 0; j < 8; ++j) f[j] = __uint_as_float((unsigned)v[j] << 16);
}

__global__ __launch_bounds__(256) void agg_relu_sh(const unsigned short* __restrict__ hw,
                                                   const int2* __restrict__ csr2,
                                                   const int* __restrict__ offs,
                                                   const float* __restrict__ dis,
                                                   const float* __restrict__ bias,
                                                   unsigned short* __restrict__ out,
                                                   int N, int Mpad) {
    int b = blockIdx.x;
    int shard = b & 7;
    int tid = threadIdx.x;
    int wave = tid >> 6, lane = tid & 63;
    int cluster = lane >> 3;
    int sub = lane & 7;
    int node = (b >> 3) * 32 + wave * 8 + cluster;
    int c0 = shard * 64 + sub * 8;
    if (node >= N) {
        if (node < Mpad) {
            u16x8 z = {0, 0, 0, 0, 0, 0, 0, 0};
            *(u16x8*)&out[(size_t)node * HID + c0] = z;
        }
        return;
    }

    const char* hwb = (const char*)hw + c0 * 2;
    float dn = dis[node];
    int e0 = offs[node], e1 = offs[node + 1];

    float acc[8];
    {
        u16x8 sv = *(const u16x8*)&hw[(size_t)node * HID + c0];
        float g[8];
        cvt8(sv, g);
        float4 bb0 = *(const float4*)&bias[c0];
        float4 bb1 = *(const float4*)&bias[c0 + 4];
        float dis2 = dn * dn;
        acc[0] = g[0] * dis2 + bb0.x; acc[1] = g[1] * dis2 + bb0.y;
        acc[2] = g[2] * dis2 + bb0.z; acc[3] = g[3] * dis2 + bb0.w;
        acc[4] = g[4] * dis2 + bb1.x; acc[5] = g[5] * dis2 + bb1.y;
        acc[6] = g[6] * dis2 + bb1.z; acc[7] = g[7] * dis2 + bb1.w;
    }

    for (int e = e0; e < e1; e += 4) {
        int off[4]; float wgt[4];
#pragma unroll
        for (int t = 0; t < 4; ++t) {
            int ee = e + t;
            int ec = (ee < e1) ? ee : (e1 - 1);
            int2 rec = csr2[ec];
            off[t] = rec.x;
            wgt[t] = (ee < e1) ? __int_as_float(rec.y) : 0.f;
        }
        u16x8 v[4];
#pragma unroll
        for (int t = 0; t < 4; ++t)
            v[t] = *(const u16x8*)(hwb + off[t]);
#pragma unroll
        for (int t = 0; t < 4; ++t) {
            float g[8];
            cvt8(v[t], g);
#pragma unroll
            for (int u = 0; u < 8; ++u) acc[u] += g[u] * wgt[t];
        }
    }

    unsigned short o[8];
#pragma unroll
    for (int t = 0; t < 8; ++t) {
        __hip_bfloat16 v = __float2bfloat16(fmaxf(acc[t], 0.f));
        o[t] = *(unsigned short*)&v;
    }
    *(u16x8*)&out[(size_t)node * HID + c0] = *(u16x8*)o;
}

// Layer-2 sharded aggregation + fused heads.
__global__ __launch_bounds__(256) void agg_heads_sh(const unsigned short* __restrict__ hw,
                                                    const int2* __restrict__ csr2,
                                                    const int* __restrict__ offs,
                                                    const float* __restrict__ dis,
                                                    const float* __restrict__ bias,
                                                    const float* __restrict__ Wo,
                                                    const float* __restrict__ Ww,
                                                    float* __restrict__ out, int N) {
    int b = blockIdx.x;
    int shard = b & 7;
    int tid = threadIdx.x;
    int wave = tid >> 6, lane = tid & 63;
    int cluster = lane >> 3;
    int sub = lane & 7;
    int node = (b >> 3) * 32 + wave * 8 + cluster;
    if (node >= N) return;
    int c0 = shard * 64 + sub * 8;

    const char* hwb = (const char*)hw + c0 * 2;
    float dn = dis[node];
    int e0 = offs[node], e1 = offs[node + 1];

    float acc[8];
    {
        u16x8 sv = *(const u16x8*)&hw[(size_t)node * HID + c0];
        float g[8];
        cvt8(sv, g);
        float4 bb0 = *(const float4*)&bias[c0];
        float4 bb1 = *(const float4*)&bias[c0 + 4];
        float dis2 = dn * dn;
        acc[0] = g[0] * dis2 + bb0.x; acc[1] = g[1] * dis2 + bb0.y;
        acc[2] = g[2] * dis2 + bb0.z; acc[3] = g[3] * dis2 + bb0.w;
        acc[4] = g[4] * dis2 + bb1.x; acc[5] = g[5] * dis2 + bb1.y;
        acc[6] = g[6] * dis2 + bb1.z; acc[7] = g[7] * dis2 + bb1.w;
    }

    for (int e = e0; e < e1; e += 4) {
        int off[4]; float wgt[4];
#pragma unroll
        for (int t = 0; t < 4; ++t) {
            int ee = e + t;
            int ec = (ee < e1) ? ee : (e1 - 1);
            int2 rec = csr2[ec];
            off[t] = rec.x;
            wgt[t] = (ee < e1) ? __int_as_float(rec.y) : 0.f;
        }
        u16x8 v[4];
#pragma unroll
        for (int t = 0; t < 4; ++t)
            v[t] = *(const u16x8*)(hwb + off[t]);
#pragma unroll
        for (int t = 0; t < 4; ++t) {
            float g[8];
            cvt8(v[t], g);
#pragma unroll
            for (int u = 0; u < 8; ++u) acc[u] += g[u] * wgt[t];
        }
    }

    float4 wo0 = *(const float4*)&Wo[c0];
    float4 wo1 = *(const float4*)&Wo[c0 + 4];
    float4 ww0 = *(const float4*)&Ww[c0];
    float4 ww1 = *(const float4*)&Ww[c0 + 4];
    float po = 0.f, pw = 0.f, h;
    h = fmaxf(acc[0], 0.f); po += h * wo0.x; pw += h * ww0.x;
    h = fmaxf(acc[1], 0.f); po += h * wo0.y; pw += h * ww0.y;
    h = fmaxf(acc[2], 0.f); po += h * wo0.z; pw += h * ww0.z;
    h = fmaxf(acc[3], 0.f); po += h * wo0.w; pw += h * ww0.w;
    h = fmaxf(acc[4], 0.f); po += h * wo1.x; pw += h * ww1.x;
    h = fmaxf(acc[5], 0.f); po += h * wo1.y; pw += h * ww1.y;
    h = fmaxf(acc[6], 0.f); po += h * wo1.z; pw += h * ww1.z;
    h = fmaxf(acc[7], 0.f); po += h * wo1.w; pw += h * ww1.w;

#pragma unroll
    for (int off2 = 4; off2 > 0; off2 >>= 1) {
        po += __shfl_down(po, off2);
        pw += __shfl_down(pw, off2);
    }
    if (sub == 0) {
        atomicAdd(&out[node], po);
        atomicAdd(&out[N + node], pw);
    }
}

// ---------------------------------------------------------------------------
extern "C" void kernel_launch(void* const* d_in, const int* in_sizes, int n_in,
                              void* d_out, int out_size, void* d_ws, size_t ws_size,
                              hipStream_t stream) {
    const float* x  = (const float*)d_in[0];
    const int*   ei = (const int*)d_in[1];
    const float* W1 = (const float*)d_in[2];
    const float* b1 = (const float*)d_in[3];
    const float* W2 = (const float*)d_in[4];
    const float* b2 = (const float*)d_in[5];
    const float* Wo = (const float*)d_in[6];
    const float* bo = (const float*)d_in[7];
    const float* Ww = (const float*)d_in[8];
    const float* bw = (const float*)d_in[9];

    const int N = in_sizes[0] / DIN;           // 25000
    const int E = in_sizes[1] / 2;             // 200000
    const int Mpad = (N + 127) & ~127;         // 25088
    const int Mtiles = Mpad / 128;             // 196
    const int nb = (N + 255) / 256;            // 98
    const int C1 = Mpad / 4;                   // convert blocks
    const int EJ = (E + 255) / 256;            // edge blocks

    char* ws = (char*)d_ws;
    size_t p = 0;
    auto alloc = [&](size_t bytes) -> char* {
        char* r = ws + p;
        p += (bytes + 255) & ~(size_t)255;
        return r;
    };
    int*   cnt    = (int*)alloc((size_t)N * 4);
    int*   offs   = (int*)alloc((size_t)(N + 1) * 4);
    int*   cursor = (int*)alloc((size_t)N * 4);
    int*   tmp    = (int*)alloc((size_t)N * 4);
    int*   bsum   = (int*)alloc(132 * 4);
    float* dis    = (float*)alloc((size_t)N * 4);
    int2*  csr2   = (int2*)alloc((size_t)E * 8 + 64);
    unsigned short* xb  = (unsigned short*)alloc((size_t)Mpad * 512 * 2);
    unsigned short* Wt1 = (unsigned short*)alloc((size_t)512 * 512 * 2);
    unsigned short* Wt2 = (unsigned short*)alloc((size_t)512 * 512 * 2);
    unsigned short* hw  = (unsigned short*)alloc((size_t)Mpad * 512 * 2);
    unsigned short* h1  = (unsigned short*)alloc((size_t)Mpad * 512 * 2);

    const int* src = ei;
    const int* dst = ei + E;

    hipMemsetAsync(cnt, 0, (size_t)N * 4, stream);

    prelude<<<C1 + 512 + EJ, 256, 0, stream>>>(x, xb, W1, W2, Wt1, Wt2,
                                               dst, cnt, E, N, C1);
    scanA<<<nb, 256, 0, stream>>>(cnt, tmp, bsum, N);
    scanB<<<nb, 256, 0, stream>>>(cnt, tmp, bsum, offs, cursor, dis,
                                  (float*)d_out, bo, bw, N, nb);

    const int G = 8 * ((Mtiles + 7) / 8) * 2;       // 400 gemm blocks
    // layer-1 GEMM with the CSR fill hidden inside the same launch
    gemm_fill<<<G + EJ, 256, 0, stream>>>((const short*)xb, (const short*)Wt1, hw,
                                          Mtiles, G, src, dst, cursor, dis, csr2, E);
    agg_relu_sh<<<8 * (Mpad / 32), 256, 0, stream>>>(hw, csr2, offs, dis, b1, h1, N, Mpad);
    gemm_bf16<<<G, 256, 0, stream>>>((const short*)h1, (const short*)Wt2, hw, Mtiles);
    agg_heads_sh<<<8 * ((N + 31) / 32), 256, 0, stream>>>(hw, csr2, offs, dis, b2,
                                                          Wo, Ww, (float*)d_out, N);
}